// Round 3
// baseline (723.169 us; speedup 1.0000x reference)
//
#include <hip/hip_runtime.h>
#include <math.h>

#define NN 16384
#define EE 262144
#define FF 32
#define HH 128
#define BB 16
#define DI 256
#define DS 16
#define DC 4
#define DTR 8
#define OUTW 1552
#define NCH 256
#define CHLEN 64    // NCH*CHLEN == NN

// ---------------------------------------------------------------- utilities
__device__ __forceinline__ float siluf(float v) { return v / (1.f + __expf(-v)); }
__device__ __forceinline__ float softplusf(float v) {
    return fmaxf(v, 0.f) + __logf(1.f + __expf(-fabsf(v)));
}

// ---------------------------------------------------------------- zero scratch (replaces 3 memsets)
__global__ void zero_kernel(int* __restrict__ cnt, float* __restrict__ ge,
                            int* __restrict__ counts) {
    int idx = blockIdx.x * blockDim.x + threadIdx.x;
    if (idx < NN) cnt[idx] = 0;
    if (idx < BB * HH) ge[idx] = 0.f;
    if (idx < BB) counts[idx] = 0;
}

// ---------------------------------------------------------------- CSR build
__global__ void deg_kernel(const int* __restrict__ dst, int* __restrict__ cnt) {
    int e = blockIdx.x * blockDim.x + threadIdx.x;
    if (e < EE) atomicAdd(&cnt[dst[e]], 1);
}

__global__ __launch_bounds__(1024) void prefix_kernel(const int* __restrict__ cnt,
                                                      int* __restrict__ rowptr,
                                                      int* __restrict__ cursor,
                                                      float* __restrict__ dinv) {
    __shared__ int part[1024];
    int tid = threadIdx.x;
    int4 c4[4];
#pragma unroll
    for (int j = 0; j < 4; j++) c4[j] = ((const int4*)cnt)[tid * 4 + j];
    int v[16] = {c4[0].x, c4[0].y, c4[0].z, c4[0].w, c4[1].x, c4[1].y, c4[1].z, c4[1].w,
                 c4[2].x, c4[2].y, c4[2].z, c4[2].w, c4[3].x, c4[3].y, c4[3].z, c4[3].w};
    int s = 0;
#pragma unroll
    for (int j = 0; j < 16; j++) s += v[j];
    part[tid] = s;
    __syncthreads();
    for (int off = 1; off < 1024; off <<= 1) {
        int t = (tid >= off) ? part[tid - off] : 0;
        __syncthreads();
        part[tid] += t;
        __syncthreads();
    }
    int running = part[tid] - s;
    int rp[16];
    float dv[16];
#pragma unroll
    for (int j = 0; j < 16; j++) {
        rp[j] = running;
        running += v[j];
        dv[j] = rsqrtf((float)(v[j] + 1));  // +1 self loop
    }
#pragma unroll
    for (int j = 0; j < 4; j++) {
        int4 r4; r4.x = rp[j*4]; r4.y = rp[j*4+1]; r4.z = rp[j*4+2]; r4.w = rp[j*4+3];
        ((int4*)rowptr)[tid * 4 + j] = r4;
        ((int4*)cursor)[tid * 4 + j] = r4;
        float4 d4; d4.x = dv[j*4]; d4.y = dv[j*4+1]; d4.z = dv[j*4+2]; d4.w = dv[j*4+3];
        ((float4*)dinv)[tid * 4 + j] = d4;
    }
    if (tid == 1023) rowptr[NN] = part[1023];
}

__global__ void scatter_kernel(const int* __restrict__ src, const int* __restrict__ dst,
                               int* __restrict__ cursor, int* __restrict__ col) {
    int e = blockIdx.x * blockDim.x + threadIdx.x;
    if (e < EE) {
        int d = dst[e];
        int pos = atomicAdd(&cursor[d], 1);
        col[pos] = src[e];
    }
}

// ---------------------------------------------------------------- GEMM (fp32, 64x64 tile)
__global__ __launch_bounds__(256) void gemm_k(const float* __restrict__ A,
                                              const float* __restrict__ B,
                                              const float* __restrict__ bias,
                                              float* __restrict__ C,
                                              int M, int Nn, int K, int act) {
    __shared__ float As[16][68];
    __shared__ float Bs[16][68];
    int tid = threadIdx.x;
    int m0 = blockIdx.y * 64;
    int n0 = blockIdx.x * 64;
    int ty = tid >> 4, tx = tid & 15;
    float acc[4][4] = {{0.f}};
    for (int k0 = 0; k0 < K; k0 += 16) {
#pragma unroll
        for (int l = 0; l < 4; l++) {
            int idx = tid + l * 256;
            int i = idx >> 4, j = idx & 15;
            As[j][i] = A[(size_t)(m0 + i) * K + k0 + j];
        }
#pragma unroll
        for (int l = 0; l < 4; l++) {
            int idx = tid + l * 256;
            int i = idx >> 6, j = idx & 63;
            int n = n0 + j;
            Bs[i][j] = (n < Nn) ? B[(size_t)(k0 + i) * Nn + n] : 0.f;
        }
        __syncthreads();
#pragma unroll
        for (int kk = 0; kk < 16; kk++) {
            float4 a4 = *(const float4*)&As[kk][ty * 4];
            float4 b4 = *(const float4*)&Bs[kk][tx * 4];
            float av[4] = {a4.x, a4.y, a4.z, a4.w};
            float bv[4] = {b4.x, b4.y, b4.z, b4.w};
#pragma unroll
            for (int r = 0; r < 4; r++)
#pragma unroll
                for (int c = 0; c < 4; c++) acc[r][c] = fmaf(av[r], bv[c], acc[r][c]);
        }
        __syncthreads();
    }
    int nb = n0 + tx * 4;
    if (nb < Nn) {
        float4 bi4 = {0.f, 0.f, 0.f, 0.f};
        if (bias) bi4 = *(const float4*)&bias[nb];
#pragma unroll
        for (int r = 0; r < 4; r++) {
            int m = m0 + ty * 4 + r;
            float4 v;
            v.x = acc[r][0] + bi4.x; v.y = acc[r][1] + bi4.y;
            v.z = acc[r][2] + bi4.z; v.w = acc[r][3] + bi4.w;
            if (act == 1) {
                v.x = fmaxf(v.x, 0.f); v.y = fmaxf(v.y, 0.f);
                v.z = fmaxf(v.z, 0.f); v.w = fmaxf(v.w, 0.f);
            }
            *(float4*)&C[(size_t)m * Nn + nb] = v;
        }
    }
}

// ---------------------------------------------------------------- fused inproj GEMM + conv + silu
// 128x128 tile of xz^T computed per block; x-half blocks (n0<256) apply the 4-tap causal
// conv + silu entirely in LDS (halo rows m0-3..m0-1 recomputed in-loop, same summation
// order as the main GEMM -> bit-identical) and store xst directly. z-half blocks store
// silu(z) directly. The 32MB xz intermediate never touches HBM.
union SMemU {
    struct { float As[16][132]; float Bs[16][132]; float Ah[16][4]; } k;
    float Cl[128][137];
};

__global__ __launch_bounds__(512, 4) void gemm_inproj_conv(const float* __restrict__ A,
                                                           const float* __restrict__ B,
                                                           const float* __restrict__ cw,
                                                           const float* __restrict__ cb,
                                                           float* __restrict__ xst,
                                                           float* __restrict__ szt) {
    __shared__ SMemU sm;
    int tid = threadIdx.x;
    int m0 = blockIdx.y * 128;   // time tile
    int n0 = blockIdx.x * 128;   // channel tile (0,128 = x; 256,384 = z)
    int ty = tid >> 4;           // 0..31 -> m rows ty*4..ty*4+3
    int tx = tid & 15;           // n cols tx*4 and 64+tx*4
    const bool xhalf = (n0 < 256);
    float acc[4][8] = {{0.f}};
    float hacc = 0.f;            // halo: xz[m0-3+hr][n0+n] for tid<384
    for (int k0 = 0; k0 < HH; k0 += 16) {
        {   // A: 128 m x 16 k, one float4 per thread -> As[k][m]
            int m = tid >> 2;
            int kc = (tid & 3) * 4;
            float4 a = *(const float4*)&A[(size_t)(m0 + m) * HH + k0 + kc];
            sm.k.As[kc + 0][m] = a.x; sm.k.As[kc + 1][m] = a.y;
            sm.k.As[kc + 2][m] = a.z; sm.k.As[kc + 3][m] = a.w;
        }
        {   // B: 16 k x 128 n, one float4 per thread
            int krow = tid >> 5;
            int c4 = (tid & 31) * 4;
            *(float4*)&sm.k.Bs[krow][c4] = *(const float4*)&B[(size_t)(k0 + krow) * 512 + n0 + c4];
        }
        if (xhalf && tid < 48) {   // halo A rows m0-3..m0-1 (zero-padded at t<0)
            int hr = tid >> 4, kk = tid & 15;
            int gm = m0 - 3 + hr;
            sm.k.Ah[kk][hr] = (gm >= 0) ? A[(size_t)gm * HH + k0 + kk] : 0.f;
        }
        __syncthreads();
#pragma unroll
        for (int kk = 0; kk < 16; kk++) {
            float4 a4 = *(const float4*)&sm.k.As[kk][ty * 4];
            float4 b0 = *(const float4*)&sm.k.Bs[kk][tx * 4];
            float4 b1 = *(const float4*)&sm.k.Bs[kk][64 + tx * 4];
            float av[4] = {a4.x, a4.y, a4.z, a4.w};
            float bv[8] = {b0.x, b0.y, b0.z, b0.w, b1.x, b1.y, b1.z, b1.w};
#pragma unroll
            for (int r = 0; r < 4; r++)
#pragma unroll
                for (int c = 0; c < 8; c++) acc[r][c] = fmaf(av[r], bv[c], acc[r][c]);
        }
        if (xhalf && tid < 384) {  // halo dot, same kk-inner/k0-outer order as main loop
            int hr = tid >> 7;     // 0..2
            int nl = tid & 127;
#pragma unroll
            for (int kk = 0; kk < 16; kk++)
                hacc = fmaf(sm.k.Ah[kk][hr], sm.k.Bs[kk][nl], hacc);
        }
        __syncthreads();
    }
    if (xhalf) {
        // park xz tile in LDS: Cl[nl][3+ml] = xz[m0+ml][n0+nl]; halo at Cl[nl][0..2]
#pragma unroll
        for (int cc = 0; cc < 4; cc++) {
#pragma unroll
            for (int r = 0; r < 4; r++) {
                sm.Cl[tx * 4 + cc][3 + ty * 4 + r] = acc[r][cc];
                sm.Cl[64 + tx * 4 + cc][3 + ty * 4 + r] = acc[r][cc + 4];
            }
        }
        if (tid < 384) sm.Cl[tid & 127][tid >> 7] = hacc;
        __syncthreads();
        // conv + silu + transposed store (each thread: 8 channels x 4 consecutive t)
#pragma unroll
        for (int half = 0; half < 2; half++) {
#pragma unroll
            for (int cc = 0; cc < 4; cc++) {
                int nl = half * 64 + tx * 4 + cc;
                int d = n0 + nl;
                float w0 = cw[d * DC + 0], w1 = cw[d * DC + 1];
                float w2 = cw[d * DC + 2], w3 = cw[d * DC + 3];
                float bcv = cb[d];
                const float* cp = &sm.Cl[nl][ty * 4];
                float c0 = cp[0], c1 = cp[1], c2 = cp[2], c3 = cp[3];
                float c4_ = cp[4], c5 = cp[5], c6 = cp[6];
                float4 o;
                o.x = siluf(bcv + w0 * c0 + w1 * c1 + w2 * c2 + w3 * c3);
                o.y = siluf(bcv + w0 * c1 + w1 * c2 + w2 * c3 + w3 * c4_);
                o.z = siluf(bcv + w0 * c2 + w1 * c3 + w2 * c4_ + w3 * c5);
                o.w = siluf(bcv + w0 * c3 + w1 * c4_ + w2 * c5 + w3 * c6);
                *(float4*)&xst[(size_t)d * NN + m0 + ty * 4] = o;
            }
        }
    } else {
        // z-half: silu + transposed store
#pragma unroll
        for (int cc = 0; cc < 4; cc++) {
            float4 v;
            v.x = siluf(acc[0][cc]); v.y = siluf(acc[1][cc]);
            v.z = siluf(acc[2][cc]); v.w = siluf(acc[3][cc]);
            *(float4*)&szt[(size_t)(n0 - 256 + tx * 4 + cc) * NN + m0 + ty * 4] = v;
            float4 u2;
            u2.x = siluf(acc[0][cc + 4]); u2.y = siluf(acc[1][cc + 4]);
            u2.z = siluf(acc[2][cc + 4]); u2.w = siluf(acc[3][cc + 4]);
            *(float4*)&szt[(size_t)(n0 - 256 + 64 + tx * 4 + cc) * NN + m0 + ty * 4] = u2;
        }
    }
}

// ---------------------------------------------------------------- xproj GEMM (A^T) + transposed output
__global__ __launch_bounds__(256) void gemm_at_dblt(const float* __restrict__ AT,
                                                    const float* __restrict__ B,
                                                    float* __restrict__ dblt) {
    __shared__ float As[16][68];
    __shared__ float Bs[16][68];
    __shared__ float Ct[64][41];
    int tid = threadIdx.x;
    int m0 = blockIdx.x * 64;
    int ty = tid >> 4, tx = tid & 15;
    float acc[4][4] = {{0.f}};
    for (int k0 = 0; k0 < DI; k0 += 16) {
#pragma unroll
        for (int l = 0; l < 4; l++) {
            int idx = tid + l * 256;
            int kk = idx >> 6, i = idx & 63;
            As[kk][i] = AT[(size_t)(k0 + kk) * NN + m0 + i];
        }
#pragma unroll
        for (int l = 0; l < 4; l++) {
            int idx = tid + l * 256;
            int i = idx >> 6, j = idx & 63;
            Bs[i][j] = (j < 40) ? B[(size_t)(k0 + i) * 40 + j] : 0.f;
        }
        __syncthreads();
#pragma unroll
        for (int kk = 0; kk < 16; kk++) {
            float4 a4 = *(const float4*)&As[kk][ty * 4];
            float4 b4 = *(const float4*)&Bs[kk][tx * 4];
            float av[4] = {a4.x, a4.y, a4.z, a4.w};
            float bv[4] = {b4.x, b4.y, b4.z, b4.w};
#pragma unroll
            for (int r = 0; r < 4; r++)
#pragma unroll
                for (int c = 0; c < 4; c++) acc[r][c] = fmaf(av[r], bv[c], acc[r][c]);
        }
        __syncthreads();
    }
    if (tx * 4 < 40) {
#pragma unroll
        for (int r = 0; r < 4; r++) {
            int m = ty * 4 + r;
            Ct[m][tx * 4 + 0] = acc[r][0];
            Ct[m][tx * 4 + 1] = acc[r][1];
            Ct[m][tx * 4 + 2] = acc[r][2];
            Ct[m][tx * 4 + 3] = acc[r][3];
        }
    }
    __syncthreads();
#pragma unroll
    for (int l = 0; l < 10; l++) {
        int idx = tid + l * 256;
        int n = idx >> 6, m = idx & 63;
        dblt[(size_t)n * NN + m0 + m] = Ct[m][n];
    }
}

// ---------------------------------------------------------------- fused W_out GEMM + add + LayerNorm + POOL
__global__ __launch_bounds__(256) void gemm_at_ln_pool(const float* __restrict__ AT,
                                                       const float* __restrict__ B,
                                                       const float* __restrict__ hg,
                                                       const float* __restrict__ gamma,
                                                       const float* __restrict__ beta,
                                                       const int* __restrict__ batch,
                                                       float* __restrict__ ge,
                                                       int* __restrict__ counts) {
    __shared__ float As[16][36];
    __shared__ float Bs[16][132];
    __shared__ float lnb[32][132];
    __shared__ int gb[32];
    int tid = threadIdx.x;
    int m0 = blockIdx.x * 32;
    int ty = tid >> 4, tx = tid & 15;
    float acc[2][8] = {{0.f}};
    for (int k0 = 0; k0 < 256; k0 += 16) {
        {
            int idx = tid * 2;
            int kk = idx >> 5, i = idx & 31;
            As[kk][i] = AT[(size_t)(k0 + kk) * NN + m0 + i];
            As[kk][i + 1] = AT[(size_t)(k0 + kk) * NN + m0 + i + 1];
        }
        {
            int krow = tid >> 4;
            int c8 = (tid & 15) * 8;
            const float* bp = &B[(size_t)(k0 + krow) * HH + c8];
            *(float4*)&Bs[krow][c8] = *(const float4*)bp;
            *(float4*)&Bs[krow][c8 + 4] = *(const float4*)(bp + 4);
        }
        __syncthreads();
#pragma unroll
        for (int kk = 0; kk < 16; kk++) {
            float a0 = As[kk][ty * 2];
            float a1 = As[kk][ty * 2 + 1];
            float4 b0 = *(const float4*)&Bs[kk][tx * 4];
            float4 b1 = *(const float4*)&Bs[kk][64 + tx * 4];
            float bv[8] = {b0.x, b0.y, b0.z, b0.w, b1.x, b1.y, b1.z, b1.w};
#pragma unroll
            for (int c = 0; c < 8; c++) {
                acc[0][c] = fmaf(a0, bv[c], acc[0][c]);
                acc[1][c] = fmaf(a1, bv[c], acc[1][c]);
            }
        }
        __syncthreads();
    }
    if (tid < 32) gb[tid] = batch[m0 + tid];
    float4 g0 = *(const float4*)&gamma[tx * 4];
    float4 g1 = *(const float4*)&gamma[64 + tx * 4];
    float4 be0 = *(const float4*)&beta[tx * 4];
    float4 be1 = *(const float4*)&beta[64 + tx * 4];
    float gv[8] = {g0.x, g0.y, g0.z, g0.w, g1.x, g1.y, g1.z, g1.w};
    float bv[8] = {be0.x, be0.y, be0.z, be0.w, be1.x, be1.y, be1.z, be1.w};
#pragma unroll
    for (int r = 0; r < 2; r++) {
        int m = m0 + ty * 2 + r;
        float4 h0 = *(const float4*)&hg[(size_t)m * HH + tx * 4];
        float4 h1 = *(const float4*)&hg[(size_t)m * HH + 64 + tx * 4];
        float v[8] = {acc[r][0] + h0.x, acc[r][1] + h0.y, acc[r][2] + h0.z, acc[r][3] + h0.w,
                      acc[r][4] + h1.x, acc[r][5] + h1.y, acc[r][6] + h1.z, acc[r][7] + h1.w};
        float sum = 0.f;
#pragma unroll
        for (int c = 0; c < 8; c++) sum += v[c];
        sum += __shfl_xor(sum, 1); sum += __shfl_xor(sum, 2);
        sum += __shfl_xor(sum, 4); sum += __shfl_xor(sum, 8);
        float mu = sum * (1.f / 128.f);
        float vs = 0.f;
#pragma unroll
        for (int c = 0; c < 8; c++) { float dd = v[c] - mu; vs += dd * dd; }
        vs += __shfl_xor(vs, 1); vs += __shfl_xor(vs, 2);
        vs += __shfl_xor(vs, 4); vs += __shfl_xor(vs, 8);
        float inv = rsqrtf(vs * (1.f / 128.f) + 1e-5f);
        int lr = ty * 2 + r;
        float4 o0, o1;
        o0.x = (v[0] - mu) * inv * gv[0] + bv[0];
        o0.y = (v[1] - mu) * inv * gv[1] + bv[1];
        o0.z = (v[2] - mu) * inv * gv[2] + bv[2];
        o0.w = (v[3] - mu) * inv * gv[3] + bv[3];
        o1.x = (v[4] - mu) * inv * gv[4] + bv[4];
        o1.y = (v[5] - mu) * inv * gv[5] + bv[5];
        o1.z = (v[6] - mu) * inv * gv[6] + bv[6];
        o1.w = (v[7] - mu) * inv * gv[7] + bv[7];
        *(float4*)&lnb[lr][tx * 4] = o0;
        *(float4*)&lnb[lr][64 + tx * 4] = o1;
    }
    __syncthreads();
    if (tid < HH) {
        int f = tid;
        int gcur = gb[0];
        float acc2 = 0.f;
        int cnt = 0;
#pragma unroll 4
        for (int i = 0; i < 32; i++) {
            int g = gb[i];
            if (g != gcur) {
                atomicAdd(&ge[gcur * HH + f], acc2);
                if (f == 0) atomicAdd(&counts[gcur], cnt);
                acc2 = 0.f; cnt = 0; gcur = g;
            }
            acc2 += lnb[i][f];
            cnt++;
        }
        atomicAdd(&ge[gcur * HH + f], acc2);
        if (f == 0) atomicAdd(&counts[gcur], cnt);
    }
}

// ---------------------------------------------------------------- GCN gather, float4, 4-edge unroll
__global__ __launch_bounds__(256) void gcn_gather4(const float* __restrict__ xw,
                                                   const int* __restrict__ rowptr,
                                                   const int* __restrict__ col,
                                                   const float* __restrict__ dinv,
                                                   const float* __restrict__ b,
                                                   float* __restrict__ out) {
    int tid = threadIdx.x;
    int sub = tid & 31;
    int n = blockIdx.x * 8 + (tid >> 5);
    float dn = dinv[n];
    const float4* xw4 = (const float4*)xw;
    float4 a = xw4[(size_t)n * 32 + sub];
    float ws = dn * dn;
    float4 acc;
    acc.x = a.x * ws; acc.y = a.y * ws; acc.z = a.z * ws; acc.w = a.w * ws;
    int beg = rowptr[n], end = rowptr[n + 1];
    int e = beg;
    for (; e + 4 <= end; e += 4) {
        int s0 = col[e], s1 = col[e + 1], s2 = col[e + 2], s3 = col[e + 3];
        float w0 = dinv[s0] * dn, w1 = dinv[s1] * dn;
        float w2 = dinv[s2] * dn, w3 = dinv[s3] * dn;
        float4 v0 = xw4[(size_t)s0 * 32 + sub];
        float4 v1 = xw4[(size_t)s1 * 32 + sub];
        float4 v2 = xw4[(size_t)s2 * 32 + sub];
        float4 v3 = xw4[(size_t)s3 * 32 + sub];
        acc.x = fmaf(v0.x, w0, acc.x); acc.y = fmaf(v0.y, w0, acc.y);
        acc.z = fmaf(v0.z, w0, acc.z); acc.w = fmaf(v0.w, w0, acc.w);
        acc.x = fmaf(v1.x, w1, acc.x); acc.y = fmaf(v1.y, w1, acc.y);
        acc.z = fmaf(v1.z, w1, acc.z); acc.w = fmaf(v1.w, w1, acc.w);
        acc.x = fmaf(v2.x, w2, acc.x); acc.y = fmaf(v2.y, w2, acc.y);
        acc.z = fmaf(v2.z, w2, acc.z); acc.w = fmaf(v2.w, w2, acc.w);
        acc.x = fmaf(v3.x, w3, acc.x); acc.y = fmaf(v3.y, w3, acc.y);
        acc.z = fmaf(v3.z, w3, acc.z); acc.w = fmaf(v3.w, w3, acc.w);
    }
    for (; e < end; e++) {
        int s0 = col[e];
        float w0 = dinv[s0] * dn;
        float4 v0 = xw4[(size_t)s0 * 32 + sub];
        acc.x = fmaf(v0.x, w0, acc.x); acc.y = fmaf(v0.y, w0, acc.y);
        acc.z = fmaf(v0.z, w0, acc.z); acc.w = fmaf(v0.w, w0, acc.w);
    }
    float4 b4 = ((const float4*)b)[sub];
    acc.x = fmaxf(acc.x + b4.x, 0.f);
    acc.y = fmaxf(acc.y + b4.y, 0.f);
    acc.z = fmaxf(acc.z + b4.z, 0.f);
    acc.w = fmaxf(acc.w + b4.w, 0.f);
    ((float4*)out)[(size_t)n * 32 + sub] = acc;
}

// ---------------------------------------------------------------- Mamba scan (LDS-staged)
__global__ __launch_bounds__(256, 6) void scan_phase1(const float* __restrict__ xst,
                                                      const float* __restrict__ dblt,
                                                      const float* __restrict__ A_log,
                                                      const float* __restrict__ W_dt,
                                                      const float* __restrict__ b_dt,
                                                      float* __restrict__ chkP,
                                                      float* __restrict__ chkH) {
    __shared__ float Td[32][68];
    __shared__ float Tx[32][68];
    __shared__ float Bs[16][68];
    __shared__ float D8[8][68];
    int tid = threadIdx.x;
    int wave = tid >> 6, lane = tid & 63;
    int sg = lane & 7, dl = lane >> 3;
    int dblk = blockIdx.x, chunk = blockIdx.y;
    int t0 = chunk * CHLEN;
    int dloc = wave * 8 + dl;
    int d = dblk * 32 + dloc;
    int s0 = 2 * sg;
#pragma unroll
    for (int p = 0; p < 2; p++) {
        int linear = tid + p * 256;
        int row = linear >> 4, c4 = (linear & 15) * 4;
        *(float4*)&Tx[row][c4] = *(const float4*)&xst[(size_t)(dblk * 32 + row) * NN + t0 + c4];
    }
    if (tid < 128) {
        int r = tid >> 4, c4 = (tid & 15) * 4;
        *(float4*)&D8[r][c4] = *(const float4*)&dblt[(size_t)r * NN + t0 + c4];
    }
    {
        int s = tid >> 4, c4 = (tid & 15) * 4;
        *(float4*)&Bs[s][c4] = *(const float4*)&dblt[(size_t)(8 + s) * NN + t0 + c4];
    }
    float A0 = -expf(A_log[d * DS + s0]);
    float A1 = -expf(A_log[d * DS + s0 + 1]);
    __syncthreads();
    {   // dt tile: 32 d x 64 t
        int row = tid >> 3;
        int tb = (tid & 7) * 8;
        int dd = dblk * 32 + row;
        float bd = b_dt[dd];
        float wv[8];
#pragma unroll
        for (int j = 0; j < 8; j++) wv[j] = W_dt[j * DI + dd];
#pragma unroll
        for (int j = 0; j < 8; j++) {
            int t = tb + j;
            float acc = bd;
#pragma unroll
            for (int k = 0; k < 8; k++) acc = fmaf(D8[k][t], wv[k], acc);
            Td[row][t] = softplusf(acc);
        }
    }
    __syncthreads();
    float h0 = 0.f, h1 = 0.f, P0 = 1.f, P1 = 1.f;
    for (int i = 0; i < CHLEN; i += 4) {
        float4 d4 = *(const float4*)&Td[dloc][i];
        float4 x4 = *(const float4*)&Tx[dloc][i];
        float4 b04 = *(const float4*)&Bs[s0][i];
        float4 b14 = *(const float4*)&Bs[s0 + 1][i];
#define P1S(U) { float dtv = d4.U; float a0 = __expf(dtv * A0); float a1 = __expf(dtv * A1); \
        float dx = dtv * x4.U; h0 = fmaf(a0, h0, dx * b04.U); h1 = fmaf(a1, h1, dx * b14.U); \
        P0 *= a0; P1 *= a1; }
        P1S(x) P1S(y) P1S(z) P1S(w)
#undef P1S
    }
    int idx = chunk * 4096 + d * DS + s0;
    float2 vP; vP.x = P0; vP.y = P1;
    float2 vH; vH.x = h0; vH.y = h1;
    *(float2*)(chkP + idx) = vP;
    *(float2*)(chkH + idx) = vH;
}

// single phase2: serial over all chunks with 8-deep batched prefetch
__global__ void scan_phase2(const float* __restrict__ chkP, const float* __restrict__ chkH,
                            float* __restrict__ init) {
    int idx = blockIdx.x * blockDim.x + threadIdx.x;  // 4096 total
    float h = 0.f;
    for (int c0 = 0; c0 < NCH; c0 += 8) {
        float p[8], q[8];
#pragma unroll
        for (int j = 0; j < 8; j++) {
            p[j] = chkP[(c0 + j) * 4096 + idx];
            q[j] = chkH[(c0 + j) * 4096 + idx];
        }
#pragma unroll
        for (int j = 0; j < 8; j++) {
            init[(c0 + j) * 4096 + idx] = h;
            h = fmaf(p[j], h, q[j]);
        }
    }
}

// phase3: D8 overlaid into Cs buffer; sz prefetched into registers before the scan loop
__global__ __launch_bounds__(256, 6) void scan_phase3(const float* __restrict__ xst,
                                                      const float* __restrict__ dblt,
                                                      const float* __restrict__ A_log,
                                                      const float* __restrict__ W_dt,
                                                      const float* __restrict__ b_dt,
                                                      const float* __restrict__ init,
                                                      const float* __restrict__ D_p,
                                                      const float* __restrict__ szt,
                                                      float* __restrict__ yt) {
    __shared__ float Td[32][68];
    __shared__ float Tx[32][68];
    __shared__ float Bs[16][68];
    __shared__ float CsD8[16][68];   // rows 0..7 = D8 during dt compute; then C rows 0..15
    int tid = threadIdx.x;
    int wave = tid >> 6, lane = tid & 63;
    int sg = lane & 7, dl = lane >> 3;
    int dblk = blockIdx.x, chunk = blockIdx.y;
    int t0 = chunk * CHLEN;
    int dloc = wave * 8 + dl;
    int d = dblk * 32 + dloc;
    int s0 = 2 * sg;
#pragma unroll
    for (int p = 0; p < 2; p++) {
        int linear = tid + p * 256;
        int row = linear >> 4, c4 = (linear & 15) * 4;
        *(float4*)&Tx[row][c4] = *(const float4*)&xst[(size_t)(dblk * 32 + row) * NN + t0 + c4];
    }
    if (tid < 128) {
        int r = tid >> 4, c4 = (tid & 15) * 4;
        *(float4*)&CsD8[r][c4] = *(const float4*)&dblt[(size_t)r * NN + t0 + c4];  // D8
    }
    {
        int s = tid >> 4, c4 = (tid & 15) * 4;
        *(float4*)&Bs[s][c4] = *(const float4*)&dblt[(size_t)(8 + s) * NN + t0 + c4];
    }
    float A0 = -expf(A_log[d * DS + s0]);
    float A1 = -expf(A_log[d * DS + s0 + 1]);
    float Dd = D_p[d];
    float2 ini = *(const float2*)(init + chunk * 4096 + d * DS + s0);
    float h0 = ini.x, h1 = ini.y;
    __syncthreads();
    {   // dt tile from D8 (CsD8 rows 0..7)
        int row = tid >> 3;
        int tb = (tid & 7) * 8;
        int dd = dblk * 32 + row;
        float bd = b_dt[dd];
        float wv[8];
#pragma unroll
        for (int j = 0; j < 8; j++) wv[j] = W_dt[j * DI + dd];
#pragma unroll
        for (int j = 0; j < 8; j++) {
            int t = tb + j;
            float acc = bd;
#pragma unroll
            for (int k = 0; k < 8; k++) acc = fmaf(CsD8[k][t], wv[k], acc);
            Td[row][t] = softplusf(acc);
        }
    }
    __syncthreads();
    {   // now load C rows over the dead D8
        int s = tid >> 4, c4 = (tid & 15) * 4;
        *(float4*)&CsD8[s][c4] = *(const float4*)&dblt[(size_t)(24 + s) * NN + t0 + c4];
    }
    // prefetch sz for the store epilogue (8 independent loads, hidden under the scan)
    float szv[8];
#pragma unroll
    for (int r = 0; r < 8; r++)
        szv[r] = szt[(size_t)(dblk * 32 + wave * 8 + r) * NN + t0 + lane];
    __syncthreads();
    for (int i = 0; i < CHLEN; i += 4) {
        float4 d4 = *(const float4*)&Td[dloc][i];
        float4 x4 = *(const float4*)&Tx[dloc][i];
        float4 b04 = *(const float4*)&Bs[s0][i];
        float4 b14 = *(const float4*)&Bs[s0 + 1][i];
        float4 c04 = *(const float4*)&CsD8[s0][i];
        float4 c14 = *(const float4*)&CsD8[s0 + 1][i];
        float4 yv;
#define P3S(U) { float dtv = d4.U; float a0 = __expf(dtv * A0); float a1 = __expf(dtv * A1); \
        float dx = dtv * x4.U; h0 = fmaf(a0, h0, dx * b04.U); h1 = fmaf(a1, h1, dx * b14.U); \
        float c = fmaf(h1, c14.U, h0 * c04.U); \
        c += __shfl_xor(c, 1); c += __shfl_xor(c, 2); c += __shfl_xor(c, 4); \
        yv.U = c + Dd * x4.U; }
        P3S(x) P3S(y) P3S(z) P3S(w)
#undef P3S
        if (sg == 0) *(float4*)&Td[dloc][i] = yv;  // in-place: this wave's row only
    }
#pragma unroll
    for (int r = 0; r < 8; r++) {
        int row = wave * 8 + r;
        yt[(size_t)(dblk * 32 + row) * NN + t0 + lane] = Td[row][lane] * szv[r];
    }
}

// ---------------------------------------------------------------- output heads (ge_norm folded in)
__global__ void heads_kernel(const float* __restrict__ ge, const int* __restrict__ counts,
                             const float* Wc, const float* bc, const float* Wh, const float* bh,
                             const float* Wt, const float* bt, const float* Wp1, const float* bp1,
                             const float* Wp2, const float* bp2, const float* Wd, const float* bd,
                             const float* Ws, const float* bs, float* __restrict__ out) {
    int col = blockIdx.x * blockDim.x + threadIdx.x;
    int b = blockIdx.y;
    if (col >= OUTW) return;
    const float* W; const float* bi; int lc, w;
    if (col < 1)         { W = Wc;  bi = bc;  lc = col;        w = 1; }
    else if (col < 5)    { W = Wh;  bi = bh;  lc = col - 1;    w = 4; }
    else if (col < 8)    { W = Wt;  bi = bt;  lc = col - 5;    w = 3; }
    else if (col < 520)  { W = Wp1; bi = bp1; lc = col - 8;    w = 512; }
    else if (col < 1032) { W = Wp2; bi = bp2; lc = col - 520;  w = 512; }
    else if (col < 1544) { W = Wd;  bi = bd;  lc = col - 1032; w = 512; }
    else                 { W = Ws;  bi = bs;  lc = col - 1544; w = 8; }
    float scale = 1.f / fmaxf((float)counts[b], 1.f);
    float dot = 0.f;
#pragma unroll 8
    for (int f = 0; f < HH; f++) dot = fmaf(ge[b * HH + f], W[f * w + lc], dot);
    out[(size_t)b * OUTW + col] = bi[lc] + scale * dot;
}

// ---------------------------------------------------------------- launch
extern "C" void kernel_launch(void* const* d_in, const int* in_sizes, int n_in,
                              void* d_out, int out_size, void* d_ws, size_t ws_size,
                              hipStream_t stream) {
    const float* nf      = (const float*)d_in[0];
    const int*   ei      = (const int*)d_in[1];
    const int*   batch   = (const int*)d_in[2];
    const float* W_in    = (const float*)d_in[3];
    const float* b_in    = (const float*)d_in[4];
    const float* W_g1    = (const float*)d_in[5];
    const float* b_g1    = (const float*)d_in[6];
    const float* W_g2    = (const float*)d_in[7];
    const float* b_g2    = (const float*)d_in[8];
    const float* W_inproj= (const float*)d_in[9];
    const float* conv_w  = (const float*)d_in[10];
    const float* conv_b  = (const float*)d_in[11];
    const float* W_xproj = (const float*)d_in[12];
    const float* W_dt    = (const float*)d_in[13];
    const float* b_dt    = (const float*)d_in[14];
    const float* A_log   = (const float*)d_in[15];
    const float* D_p     = (const float*)d_in[16];
    const float* W_out   = (const float*)d_in[17];
    const float* gamma   = (const float*)d_in[18];
    const float* beta    = (const float*)d_in[19];
    const float* Wc = (const float*)d_in[20]; const float* bc = (const float*)d_in[21];
    const float* Wh = (const float*)d_in[22]; const float* bh = (const float*)d_in[23];
    const float* Wt = (const float*)d_in[24]; const float* bt = (const float*)d_in[25];
    const float* Wp1= (const float*)d_in[26]; const float* bp1= (const float*)d_in[27];
    const float* Wp2= (const float*)d_in[28]; const float* bp2= (const float*)d_in[29];
    const float* Wd = (const float*)d_in[30]; const float* bd = (const float*)d_in[31];
    const float* Ws = (const float*)d_in[32]; const float* bs = (const float*)d_in[33];

    const int* e_src = ei;
    const int* e_dst = ei + EE;

    // workspace layout (floats, then ints)
    float* w = (float*)d_ws;
    size_t o = 0;
    float* F0   = w + o; o += (size_t)NN * HH;   // dead during scan -> CHP/CHH
    float* F1   = w + o; o += (size_t)NN * HH;   // dead during scan -> INI
    float* F2   = w + o; o += (size_t)NN * HH;
    float* YT   = w + o; o += (size_t)NN * DI;   // y^T [DI][NN]
    float* XST  = w + o; o += (size_t)NN * DI;   // x (conv+silu), transposed [DI][NN]
    float* SZT  = w + o; o += (size_t)NN * DI;   // silu(z), transposed [DI][NN]
    float* DBLT = w + o; o += (size_t)NN * 40;   // [40][NN]; 0..7 = dt-proj^T, 8..23 = B^T, 24..39 = C^T
    float* GE   = w + o; o += BB * HH;
    float* DINV = w + o; o += NN;
    int* ip = (int*)(w + o);
    int* CNT    = ip; ip += NN;
    int* ROWPTR = ip; ip += NN + 1;
    int* CURSOR = ip; ip += NN;
    int* COL    = ip; ip += EE;
    int* COUNTS = ip; ip += BB;

    // overlays (regions dead during the scan)
    float* CHP  = F0;                         // NCH*4096 = 1M floats
    float* CHH  = F0 + (size_t)NCH * 4096;    // 1M floats (F0 holds 2M)
    float* INI  = F1;                         // NCH*4096 = 1M floats (F1 holds 2M)

    // zero scratch (single kernel instead of 3 memsets)
    zero_kernel<<<(NN + 255) / 256, 256, 0, stream>>>(CNT, GE, COUNTS);

    // CSR build
    deg_kernel<<<EE / 256, 256, 0, stream>>>(e_dst, CNT);
    prefix_kernel<<<1, 1024, 0, stream>>>(CNT, ROWPTR, CURSOR, DINV);
    scatter_kernel<<<EE / 256, 256, 0, stream>>>(e_src, e_dst, CURSOR, COL);

    // h0 = relu(nf @ W_in + b_in)
    gemm_k<<<dim3(2, NN / 64), 256, 0, stream>>>(nf, W_in, b_in, F0, NN, HH, FF, 1);
    // GCN layer 1
    gemm_k<<<dim3(2, NN / 64), 256, 0, stream>>>(F0, W_g1, nullptr, F1, NN, HH, HH, 0);
    gcn_gather4<<<NN / 8, 256, 0, stream>>>(F1, ROWPTR, COL, DINV, b_g1, F0);
    // GCN layer 2
    gemm_k<<<dim3(2, NN / 64), 256, 0, stream>>>(F0, W_g2, nullptr, F1, NN, HH, HH, 0);
    gcn_gather4<<<NN / 8, 256, 0, stream>>>(F1, ROWPTR, COL, DINV, b_g2, F2);  // F2 = h_gnn

    // xz = h_gnn @ W_inproj fused with conv+silu: xst, szt written directly (xz never stored)
    gemm_inproj_conv<<<dim3(4, NN / 128), 512, 0, stream>>>(F2, W_inproj, conv_w, conv_b, XST, SZT);
    // dbl = xs @ W_xproj, written directly transposed -> DBLT (fused)
    gemm_at_dblt<<<NN / 64, 256, 0, stream>>>(XST, W_xproj, DBLT);

    // Mamba scan (dt fused into phase1/phase3; single phase2)
    scan_phase1<<<dim3(8, NCH), 256, 0, stream>>>(XST, DBLT, A_log, W_dt, b_dt, CHP, CHH);
    scan_phase2<<<16, 256, 0, stream>>>(CHP, CHH, INI);
    scan_phase3<<<dim3(8, NCH), 256, 0, stream>>>(XST, DBLT, A_log, W_dt, b_dt, INI, D_p, SZT, YT);

    // h_mamba = y @ W_out; + h_gnn; LayerNorm; pooled directly into GE (h_final never stored)
    gemm_at_ln_pool<<<NN / 32, 256, 0, stream>>>(YT, W_out, F2, gamma, beta, batch, GE, COUNTS);

    // heads (ge_norm folded in)
    heads_kernel<<<dim3((OUTW + 127) / 128, BB), 128, 0, stream>>>(
        GE, COUNTS, Wc, bc, Wh, bh, Wt, bt, Wp1, bp1, Wp2, bp2, Wd, bd, Ws, bs, (float*)d_out);
}

// Round 4
// 396.023 us; speedup vs baseline: 1.8261x; 1.8261x over previous
//
#include <hip/hip_runtime.h>
#include <math.h>

#define NN 16384
#define EE 262144
#define FF 32
#define HH 128
#define BB 16
#define DI 256
#define DS 16
#define DC 4
#define DTR 8
#define OUTW 1552
#define NCH 256
#define CHLEN 64    // NCH*CHLEN == NN

// ---------------------------------------------------------------- utilities
__device__ __forceinline__ float siluf(float v) { return v / (1.f + __expf(-v)); }
__device__ __forceinline__ float softplusf(float v) {
    return fmaxf(v, 0.f) + __logf(1.f + __expf(-fabsf(v)));
}

// ---------------------------------------------------------------- zero scratch (replaces 3 memsets)
__global__ void zero_kernel(int* __restrict__ cnt, float* __restrict__ ge,
                            int* __restrict__ counts) {
    int idx = blockIdx.x * blockDim.x + threadIdx.x;
    if (idx < NN) cnt[idx] = 0;
    if (idx < BB * HH) ge[idx] = 0.f;
    if (idx < BB) counts[idx] = 0;
}

// ---------------------------------------------------------------- CSR build
__global__ void deg_kernel(const int* __restrict__ dst, int* __restrict__ cnt) {
    int e = blockIdx.x * blockDim.x + threadIdx.x;
    if (e < EE) atomicAdd(&cnt[dst[e]], 1);
}

__global__ __launch_bounds__(1024) void prefix_kernel(const int* __restrict__ cnt,
                                                      int* __restrict__ rowptr,
                                                      int* __restrict__ cursor,
                                                      float* __restrict__ dinv) {
    __shared__ int part[1024];
    int tid = threadIdx.x;
    int4 c4[4];
#pragma unroll
    for (int j = 0; j < 4; j++) c4[j] = ((const int4*)cnt)[tid * 4 + j];
    int v[16] = {c4[0].x, c4[0].y, c4[0].z, c4[0].w, c4[1].x, c4[1].y, c4[1].z, c4[1].w,
                 c4[2].x, c4[2].y, c4[2].z, c4[2].w, c4[3].x, c4[3].y, c4[3].z, c4[3].w};
    int s = 0;
#pragma unroll
    for (int j = 0; j < 16; j++) s += v[j];
    part[tid] = s;
    __syncthreads();
    for (int off = 1; off < 1024; off <<= 1) {
        int t = (tid >= off) ? part[tid - off] : 0;
        __syncthreads();
        part[tid] += t;
        __syncthreads();
    }
    int running = part[tid] - s;
    int rp[16];
    float dv[16];
#pragma unroll
    for (int j = 0; j < 16; j++) {
        rp[j] = running;
        running += v[j];
        dv[j] = rsqrtf((float)(v[j] + 1));  // +1 self loop
    }
#pragma unroll
    for (int j = 0; j < 4; j++) {
        int4 r4; r4.x = rp[j*4]; r4.y = rp[j*4+1]; r4.z = rp[j*4+2]; r4.w = rp[j*4+3];
        ((int4*)rowptr)[tid * 4 + j] = r4;
        ((int4*)cursor)[tid * 4 + j] = r4;
        float4 d4; d4.x = dv[j*4]; d4.y = dv[j*4+1]; d4.z = dv[j*4+2]; d4.w = dv[j*4+3];
        ((float4*)dinv)[tid * 4 + j] = d4;
    }
    if (tid == 1023) rowptr[NN] = part[1023];
}

__global__ void scatter_kernel(const int* __restrict__ src, const int* __restrict__ dst,
                               int* __restrict__ cursor, int* __restrict__ col) {
    int e = blockIdx.x * blockDim.x + threadIdx.x;
    if (e < EE) {
        int d = dst[e];
        int pos = atomicAdd(&cursor[d], 1);
        col[pos] = src[e];
    }
}

// ---------------------------------------------------------------- GEMM (fp32, 64x64 tile)
__global__ __launch_bounds__(256) void gemm_k(const float* __restrict__ A,
                                              const float* __restrict__ B,
                                              const float* __restrict__ bias,
                                              float* __restrict__ C,
                                              int M, int Nn, int K, int act) {
    __shared__ float As[16][68];
    __shared__ float Bs[16][68];
    int tid = threadIdx.x;
    int m0 = blockIdx.y * 64;
    int n0 = blockIdx.x * 64;
    int ty = tid >> 4, tx = tid & 15;
    float acc[4][4] = {{0.f}};
    for (int k0 = 0; k0 < K; k0 += 16) {
#pragma unroll
        for (int l = 0; l < 4; l++) {
            int idx = tid + l * 256;
            int i = idx >> 4, j = idx & 15;
            As[j][i] = A[(size_t)(m0 + i) * K + k0 + j];
        }
#pragma unroll
        for (int l = 0; l < 4; l++) {
            int idx = tid + l * 256;
            int i = idx >> 6, j = idx & 63;
            int n = n0 + j;
            Bs[i][j] = (n < Nn) ? B[(size_t)(k0 + i) * Nn + n] : 0.f;
        }
        __syncthreads();
#pragma unroll
        for (int kk = 0; kk < 16; kk++) {
            float4 a4 = *(const float4*)&As[kk][ty * 4];
            float4 b4 = *(const float4*)&Bs[kk][tx * 4];
            float av[4] = {a4.x, a4.y, a4.z, a4.w};
            float bv[4] = {b4.x, b4.y, b4.z, b4.w};
#pragma unroll
            for (int r = 0; r < 4; r++)
#pragma unroll
                for (int c = 0; c < 4; c++) acc[r][c] = fmaf(av[r], bv[c], acc[r][c]);
        }
        __syncthreads();
    }
    int nb = n0 + tx * 4;
    if (nb < Nn) {
        float4 bi4 = {0.f, 0.f, 0.f, 0.f};
        if (bias) bi4 = *(const float4*)&bias[nb];
#pragma unroll
        for (int r = 0; r < 4; r++) {
            int m = m0 + ty * 4 + r;
            float4 v;
            v.x = acc[r][0] + bi4.x; v.y = acc[r][1] + bi4.y;
            v.z = acc[r][2] + bi4.z; v.w = acc[r][3] + bi4.w;
            if (act == 1) {
                v.x = fmaxf(v.x, 0.f); v.y = fmaxf(v.y, 0.f);
                v.z = fmaxf(v.z, 0.f); v.w = fmaxf(v.w, 0.f);
            }
            *(float4*)&C[(size_t)m * Nn + nb] = v;
        }
    }
}

// ---------------------------------------------------------------- fused relu(nf@W_in+b) @ W_g1
// h0 has exactly one consumer -> compute the 64-row h tile in LDS, then standard
// 64x64 K=128 GEMM from LDS. h0 never touches HBM. LDS ~59KB -> 2 blocks/CU.
union SMemIn {
    struct { float Ns[64][33]; float Ws[32][132]; } s1;   // step-1 staging
    float Bs[16][68];                                     // step-2 W_g1 chunk
};

__global__ __launch_bounds__(256) void gemm_in_g1(const float* __restrict__ nf,
                                                  const float* __restrict__ W_in,
                                                  const float* __restrict__ b_in,
                                                  const float* __restrict__ W_g1,
                                                  float* __restrict__ out) {
    __shared__ SMemIn sm;
    __shared__ float Hs[128][68];   // h^T: Hs[k][m]
    int tid = threadIdx.x;
    int m0 = blockIdx.y * 64;
    int n0 = blockIdx.x * 64;
    int ty = tid >> 4, tx = tid & 15;
    // stage nf tile (64x32) and W_in (32x128)
#pragma unroll
    for (int l = 0; l < 2; l++) {
        int q = tid + l * 256;
        int r = q >> 3, c4 = (q & 7) * 4;
        *(float4*)&sm.s1.Ns[r][c4] = *(const float4*)&nf[(size_t)(m0 + r) * FF + c4];
    }
#pragma unroll
    for (int l = 0; l < 4; l++) {
        int q = tid + l * 256;
        int r = q >> 5, c4 = (q & 31) * 4;
        *(float4*)&sm.s1.Ws[r][c4] = *(const float4*)&W_in[(size_t)r * HH + c4];
    }
    __syncthreads();
    // step 1: h = relu(nf@W_in + b); each thread 4 rows x 8 cols -> Hs transposed
    {
        float4 b0 = *(const float4*)&b_in[tx * 4];
        float4 b1 = *(const float4*)&b_in[64 + tx * 4];
        float hacc[4][8];
#pragma unroll
        for (int r = 0; r < 4; r++) {
            hacc[r][0] = b0.x; hacc[r][1] = b0.y; hacc[r][2] = b0.z; hacc[r][3] = b0.w;
            hacc[r][4] = b1.x; hacc[r][5] = b1.y; hacc[r][6] = b1.z; hacc[r][7] = b1.w;
        }
#pragma unroll
        for (int k = 0; k < FF; k++) {
            float av[4];
#pragma unroll
            for (int r = 0; r < 4; r++) av[r] = sm.s1.Ns[ty * 4 + r][k];
            float wv[8];
#pragma unroll
            for (int c = 0; c < 4; c++) {
                wv[c]     = sm.s1.Ws[k][tx * 4 + c];
                wv[c + 4] = sm.s1.Ws[k][64 + tx * 4 + c];
            }
#pragma unroll
            for (int r = 0; r < 4; r++)
#pragma unroll
                for (int c = 0; c < 8; c++) hacc[r][c] = fmaf(av[r], wv[c], hacc[r][c]);
        }
#pragma unroll
        for (int r = 0; r < 4; r++)
#pragma unroll
            for (int c = 0; c < 4; c++) {
                Hs[tx * 4 + c][ty * 4 + r]      = fmaxf(hacc[r][c], 0.f);
                Hs[64 + tx * 4 + c][ty * 4 + r] = fmaxf(hacc[r][c + 4], 0.f);
            }
    }
    __syncthreads();   // Hs ready; Ns/Ws dead -> Bs may overwrite
    // step 2: out[m0:m0+64][n0:n0+64] = h @ W_g1
    float acc[4][4] = {{0.f}};
    for (int k0 = 0; k0 < HH; k0 += 16) {
        *(float4*)&sm.Bs[tid >> 4][(tid & 15) * 4] =
            *(const float4*)&W_g1[(size_t)(k0 + (tid >> 4)) * HH + n0 + (tid & 15) * 4];
        __syncthreads();
#pragma unroll
        for (int kk = 0; kk < 16; kk++) {
            float4 a4 = *(const float4*)&Hs[k0 + kk][ty * 4];
            float4 b4 = *(const float4*)&sm.Bs[kk][tx * 4];
            float av[4] = {a4.x, a4.y, a4.z, a4.w};
            float bv[4] = {b4.x, b4.y, b4.z, b4.w};
#pragma unroll
            for (int r = 0; r < 4; r++)
#pragma unroll
                for (int c = 0; c < 4; c++) acc[r][c] = fmaf(av[r], bv[c], acc[r][c]);
        }
        __syncthreads();
    }
#pragma unroll
    for (int r = 0; r < 4; r++) {
        int m = m0 + ty * 4 + r;
        float4 v;
        v.x = acc[r][0]; v.y = acc[r][1]; v.z = acc[r][2]; v.w = acc[r][3];
        *(float4*)&out[(size_t)m * HH + n0 + tx * 4] = v;
    }
}

// ---------------------------------------------------------------- big-tile GEMM, 512 threads, TRANSPOSED output
__global__ __launch_bounds__(512, 4) void gemm_big512_t(const float* __restrict__ A,
                                                        const float* __restrict__ B,
                                                        float* __restrict__ CT,
                                                        int M, int Nn, int K) {
    __shared__ float As[16][132];
    __shared__ float Bs[16][132];
    int tid = threadIdx.x;
    int m0 = blockIdx.y * 128;
    int n0 = blockIdx.x * 128;
    int ty = tid >> 4;          // 0..31 -> m rows ty*4..ty*4+3
    int tx = tid & 15;          // n cols tx*4 and 64+tx*4
    float acc[4][8] = {{0.f}};
    for (int k0 = 0; k0 < K; k0 += 16) {
        {   // A: 128 m x 16 k, one float4 per thread -> As[k][m]
            int m = tid >> 2;
            int kc = (tid & 3) * 4;
            float4 a = *(const float4*)&A[(size_t)(m0 + m) * K + k0 + kc];
            As[kc + 0][m] = a.x; As[kc + 1][m] = a.y;
            As[kc + 2][m] = a.z; As[kc + 3][m] = a.w;
        }
        {   // B: 16 k x 128 n, one float4 per thread
            int krow = tid >> 5;
            int c4 = (tid & 31) * 4;
            *(float4*)&Bs[krow][c4] = *(const float4*)&B[(size_t)(k0 + krow) * Nn + n0 + c4];
        }
        __syncthreads();
#pragma unroll
        for (int kk = 0; kk < 16; kk++) {
            float4 a4 = *(const float4*)&As[kk][ty * 4];
            float4 b0 = *(const float4*)&Bs[kk][tx * 4];
            float4 b1 = *(const float4*)&Bs[kk][64 + tx * 4];
            float av[4] = {a4.x, a4.y, a4.z, a4.w};
            float bv[8] = {b0.x, b0.y, b0.z, b0.w, b1.x, b1.y, b1.z, b1.w};
#pragma unroll
            for (int r = 0; r < 4; r++)
#pragma unroll
                for (int c = 0; c < 8; c++) acc[r][c] = fmaf(av[r], bv[c], acc[r][c]);
        }
        __syncthreads();
    }
    // transposed store: CT[n][m]
#pragma unroll
    for (int cc = 0; cc < 4; cc++) {
        float4 v;
        v.x = acc[0][cc]; v.y = acc[1][cc]; v.z = acc[2][cc]; v.w = acc[3][cc];
        *(float4*)&CT[(size_t)(n0 + tx * 4 + cc) * NN + m0 + ty * 4] = v;
        float4 u;
        u.x = acc[0][cc + 4]; u.y = acc[1][cc + 4]; u.z = acc[2][cc + 4]; u.w = acc[3][cc + 4];
        *(float4*)&CT[(size_t)(n0 + 64 + tx * 4 + cc) * NN + m0 + ty * 4] = u;
    }
}

// ---------------------------------------------------------------- conv + silu over transposed xz
__global__ __launch_bounds__(256) void conv_silu_rows(const float* __restrict__ xzt,
                                                      const float* __restrict__ cw,
                                                      const float* __restrict__ cb,
                                                      float* __restrict__ xst,
                                                      float* __restrict__ szt) {
    int d = blockIdx.y;                       // 0..511 (x rows then z rows)
    int tg = blockIdx.x * 1024 + threadIdx.x * 4;
    const float* row = xzt + (size_t)d * NN;
    float4 cur = *(const float4*)&row[tg];
    if (d < DI) {
        float4 prev;
        if (tg == 0) { prev.x = 0.f; prev.y = 0.f; prev.z = 0.f; prev.w = 0.f; }
        else prev = *(const float4*)&row[tg - 4];
        float w0 = cw[d * DC + 0], w1 = cw[d * DC + 1];
        float w2 = cw[d * DC + 2], w3 = cw[d * DC + 3];
        float b = cb[d];
        float4 o;
        o.x = siluf(b + w0 * prev.y + w1 * prev.z + w2 * prev.w + w3 * cur.x);
        o.y = siluf(b + w0 * prev.z + w1 * prev.w + w2 * cur.x + w3 * cur.y);
        o.z = siluf(b + w0 * prev.w + w1 * cur.x + w2 * cur.y + w3 * cur.z);
        o.w = siluf(b + w0 * cur.x + w1 * cur.y + w2 * cur.z + w3 * cur.w);
        *(float4*)&xst[(size_t)d * NN + tg] = o;
    } else {
        float4 o;
        o.x = siluf(cur.x); o.y = siluf(cur.y); o.z = siluf(cur.z); o.w = siluf(cur.w);
        *(float4*)&szt[(size_t)(d - DI) * NN + tg] = o;
    }
}

// ---------------------------------------------------------------- xproj GEMM (A^T) + transposed output
__global__ __launch_bounds__(256) void gemm_at_dblt(const float* __restrict__ AT,
                                                    const float* __restrict__ B,
                                                    float* __restrict__ dblt) {
    __shared__ float As[16][68];
    __shared__ float Bs[16][68];
    __shared__ float Ct[64][41];
    int tid = threadIdx.x;
    int m0 = blockIdx.x * 64;
    int ty = tid >> 4, tx = tid & 15;
    float acc[4][4] = {{0.f}};
    for (int k0 = 0; k0 < DI; k0 += 16) {
#pragma unroll
        for (int l = 0; l < 4; l++) {
            int idx = tid + l * 256;
            int kk = idx >> 6, i = idx & 63;
            As[kk][i] = AT[(size_t)(k0 + kk) * NN + m0 + i];
        }
#pragma unroll
        for (int l = 0; l < 4; l++) {
            int idx = tid + l * 256;
            int i = idx >> 6, j = idx & 63;
            Bs[i][j] = (j < 40) ? B[(size_t)(k0 + i) * 40 + j] : 0.f;
        }
        __syncthreads();
#pragma unroll
        for (int kk = 0; kk < 16; kk++) {
            float4 a4 = *(const float4*)&As[kk][ty * 4];
            float4 b4 = *(const float4*)&Bs[kk][tx * 4];
            float av[4] = {a4.x, a4.y, a4.z, a4.w};
            float bv[4] = {b4.x, b4.y, b4.z, b4.w};
#pragma unroll
            for (int r = 0; r < 4; r++)
#pragma unroll
                for (int c = 0; c < 4; c++) acc[r][c] = fmaf(av[r], bv[c], acc[r][c]);
        }
        __syncthreads();
    }
    if (tx * 4 < 40) {
#pragma unroll
        for (int r = 0; r < 4; r++) {
            int m = ty * 4 + r;
            Ct[m][tx * 4 + 0] = acc[r][0];
            Ct[m][tx * 4 + 1] = acc[r][1];
            Ct[m][tx * 4 + 2] = acc[r][2];
            Ct[m][tx * 4 + 3] = acc[r][3];
        }
    }
    __syncthreads();
#pragma unroll
    for (int l = 0; l < 10; l++) {
        int idx = tid + l * 256;
        int n = idx >> 6, m = idx & 63;
        dblt[(size_t)n * NN + m0 + m] = Ct[m][n];
    }
}

// ---------------------------------------------------------------- fused W_out GEMM + add + LayerNorm + POOL
__global__ __launch_bounds__(256) void gemm_at_ln_pool(const float* __restrict__ AT,
                                                       const float* __restrict__ B,
                                                       const float* __restrict__ hg,
                                                       const float* __restrict__ gamma,
                                                       const float* __restrict__ beta,
                                                       const int* __restrict__ batch,
                                                       float* __restrict__ ge,
                                                       int* __restrict__ counts) {
    __shared__ float As[16][36];
    __shared__ float Bs[16][132];
    __shared__ float lnb[32][132];
    __shared__ int gb[32];
    int tid = threadIdx.x;
    int m0 = blockIdx.x * 32;
    int ty = tid >> 4, tx = tid & 15;
    float acc[2][8] = {{0.f}};
    for (int k0 = 0; k0 < 256; k0 += 16) {
        {
            int idx = tid * 2;
            int kk = idx >> 5, i = idx & 31;
            As[kk][i] = AT[(size_t)(k0 + kk) * NN + m0 + i];
            As[kk][i + 1] = AT[(size_t)(k0 + kk) * NN + m0 + i + 1];
        }
        {
            int krow = tid >> 4;
            int c8 = (tid & 15) * 8;
            const float* bp = &B[(size_t)(k0 + krow) * HH + c8];
            *(float4*)&Bs[krow][c8] = *(const float4*)bp;
            *(float4*)&Bs[krow][c8 + 4] = *(const float4*)(bp + 4);
        }
        __syncthreads();
#pragma unroll
        for (int kk = 0; kk < 16; kk++) {
            float a0 = As[kk][ty * 2];
            float a1 = As[kk][ty * 2 + 1];
            float4 b0 = *(const float4*)&Bs[kk][tx * 4];
            float4 b1 = *(const float4*)&Bs[kk][64 + tx * 4];
            float bv[8] = {b0.x, b0.y, b0.z, b0.w, b1.x, b1.y, b1.z, b1.w};
#pragma unroll
            for (int c = 0; c < 8; c++) {
                acc[0][c] = fmaf(a0, bv[c], acc[0][c]);
                acc[1][c] = fmaf(a1, bv[c], acc[1][c]);
            }
        }
        __syncthreads();
    }
    if (tid < 32) gb[tid] = batch[m0 + tid];
    float4 g0 = *(const float4*)&gamma[tx * 4];
    float4 g1 = *(const float4*)&gamma[64 + tx * 4];
    float4 be0 = *(const float4*)&beta[tx * 4];
    float4 be1 = *(const float4*)&beta[64 + tx * 4];
    float gv[8] = {g0.x, g0.y, g0.z, g0.w, g1.x, g1.y, g1.z, g1.w};
    float bv[8] = {be0.x, be0.y, be0.z, be0.w, be1.x, be1.y, be1.z, be1.w};
#pragma unroll
    for (int r = 0; r < 2; r++) {
        int m = m0 + ty * 2 + r;
        float4 h0 = *(const float4*)&hg[(size_t)m * HH + tx * 4];
        float4 h1 = *(const float4*)&hg[(size_t)m * HH + 64 + tx * 4];
        float v[8] = {acc[r][0] + h0.x, acc[r][1] + h0.y, acc[r][2] + h0.z, acc[r][3] + h0.w,
                      acc[r][4] + h1.x, acc[r][5] + h1.y, acc[r][6] + h1.z, acc[r][7] + h1.w};
        float sum = 0.f;
#pragma unroll
        for (int c = 0; c < 8; c++) sum += v[c];
        sum += __shfl_xor(sum, 1); sum += __shfl_xor(sum, 2);
        sum += __shfl_xor(sum, 4); sum += __shfl_xor(sum, 8);
        float mu = sum * (1.f / 128.f);
        float vs = 0.f;
#pragma unroll
        for (int c = 0; c < 8; c++) { float dd = v[c] - mu; vs += dd * dd; }
        vs += __shfl_xor(vs, 1); vs += __shfl_xor(vs, 2);
        vs += __shfl_xor(vs, 4); vs += __shfl_xor(vs, 8);
        float inv = rsqrtf(vs * (1.f / 128.f) + 1e-5f);
        int lr = ty * 2 + r;
        float4 o0, o1;
        o0.x = (v[0] - mu) * inv * gv[0] + bv[0];
        o0.y = (v[1] - mu) * inv * gv[1] + bv[1];
        o0.z = (v[2] - mu) * inv * gv[2] + bv[2];
        o0.w = (v[3] - mu) * inv * gv[3] + bv[3];
        o1.x = (v[4] - mu) * inv * gv[4] + bv[4];
        o1.y = (v[5] - mu) * inv * gv[5] + bv[5];
        o1.z = (v[6] - mu) * inv * gv[6] + bv[6];
        o1.w = (v[7] - mu) * inv * gv[7] + bv[7];
        *(float4*)&lnb[lr][tx * 4] = o0;
        *(float4*)&lnb[lr][64 + tx * 4] = o1;
    }
    __syncthreads();
    if (tid < HH) {
        int f = tid;
        int gcur = gb[0];
        float acc2 = 0.f;
        int cnt = 0;
#pragma unroll 4
        for (int i = 0; i < 32; i++) {
            int g = gb[i];
            if (g != gcur) {
                atomicAdd(&ge[gcur * HH + f], acc2);
                if (f == 0) atomicAdd(&counts[gcur], cnt);
                acc2 = 0.f; cnt = 0; gcur = g;
            }
            acc2 += lnb[i][f];
            cnt++;
        }
        atomicAdd(&ge[gcur * HH + f], acc2);
        if (f == 0) atomicAdd(&counts[gcur], cnt);
    }
}

// ---------------------------------------------------------------- GCN gather, float4, 4-edge unroll
__global__ __launch_bounds__(256) void gcn_gather4(const float* __restrict__ xw,
                                                   const int* __restrict__ rowptr,
                                                   const int* __restrict__ col,
                                                   const float* __restrict__ dinv,
                                                   const float* __restrict__ b,
                                                   float* __restrict__ out) {
    int tid = threadIdx.x;
    int sub = tid & 31;
    int n = blockIdx.x * 8 + (tid >> 5);
    float dn = dinv[n];
    const float4* xw4 = (const float4*)xw;
    float4 a = xw4[(size_t)n * 32 + sub];
    float ws = dn * dn;
    float4 acc;
    acc.x = a.x * ws; acc.y = a.y * ws; acc.z = a.z * ws; acc.w = a.w * ws;
    int beg = rowptr[n], end = rowptr[n + 1];
    int e = beg;
    for (; e + 4 <= end; e += 4) {
        int s0 = col[e], s1 = col[e + 1], s2 = col[e + 2], s3 = col[e + 3];
        float w0 = dinv[s0] * dn, w1 = dinv[s1] * dn;
        float w2 = dinv[s2] * dn, w3 = dinv[s3] * dn;
        float4 v0 = xw4[(size_t)s0 * 32 + sub];
        float4 v1 = xw4[(size_t)s1 * 32 + sub];
        float4 v2 = xw4[(size_t)s2 * 32 + sub];
        float4 v3 = xw4[(size_t)s3 * 32 + sub];
        acc.x = fmaf(v0.x, w0, acc.x); acc.y = fmaf(v0.y, w0, acc.y);
        acc.z = fmaf(v0.z, w0, acc.z); acc.w = fmaf(v0.w, w0, acc.w);
        acc.x = fmaf(v1.x, w1, acc.x); acc.y = fmaf(v1.y, w1, acc.y);
        acc.z = fmaf(v1.z, w1, acc.z); acc.w = fmaf(v1.w, w1, acc.w);
        acc.x = fmaf(v2.x, w2, acc.x); acc.y = fmaf(v2.y, w2, acc.y);
        acc.z = fmaf(v2.z, w2, acc.z); acc.w = fmaf(v2.w, w2, acc.w);
        acc.x = fmaf(v3.x, w3, acc.x); acc.y = fmaf(v3.y, w3, acc.y);
        acc.z = fmaf(v3.z, w3, acc.z); acc.w = fmaf(v3.w, w3, acc.w);
    }
    for (; e < end; e++) {
        int s0 = col[e];
        float w0 = dinv[s0] * dn;
        float4 v0 = xw4[(size_t)s0 * 32 + sub];
        acc.x = fmaf(v0.x, w0, acc.x); acc.y = fmaf(v0.y, w0, acc.y);
        acc.z = fmaf(v0.z, w0, acc.z); acc.w = fmaf(v0.w, w0, acc.w);
    }
    float4 b4 = ((const float4*)b)[sub];
    acc.x = fmaxf(acc.x + b4.x, 0.f);
    acc.y = fmaxf(acc.y + b4.y, 0.f);
    acc.z = fmaxf(acc.z + b4.z, 0.f);
    acc.w = fmaxf(acc.w + b4.w, 0.f);
    ((float4*)out)[(size_t)n * 32 + sub] = acc;
}

// ---------------------------------------------------------------- Mamba scan (LDS-staged)
__global__ __launch_bounds__(256, 6) void scan_phase1(const float* __restrict__ xst,
                                                      const float* __restrict__ dblt,
                                                      const float* __restrict__ A_log,
                                                      const float* __restrict__ W_dt,
                                                      const float* __restrict__ b_dt,
                                                      float* __restrict__ chkP,
                                                      float* __restrict__ chkH) {
    __shared__ float Td[32][68];
    __shared__ float Tx[32][68];
    __shared__ float Bs[16][68];
    __shared__ float D8[8][68];
    int tid = threadIdx.x;
    int wave = tid >> 6, lane = tid & 63;
    int sg = lane & 7, dl = lane >> 3;
    int dblk = blockIdx.x, chunk = blockIdx.y;
    int t0 = chunk * CHLEN;
    int dloc = wave * 8 + dl;
    int d = dblk * 32 + dloc;
    int s0 = 2 * sg;
#pragma unroll
    for (int p = 0; p < 2; p++) {
        int linear = tid + p * 256;
        int row = linear >> 4, c4 = (linear & 15) * 4;
        *(float4*)&Tx[row][c4] = *(const float4*)&xst[(size_t)(dblk * 32 + row) * NN + t0 + c4];
    }
    if (tid < 128) {
        int r = tid >> 4, c4 = (tid & 15) * 4;
        *(float4*)&D8[r][c4] = *(const float4*)&dblt[(size_t)r * NN + t0 + c4];
    }
    {
        int s = tid >> 4, c4 = (tid & 15) * 4;
        *(float4*)&Bs[s][c4] = *(const float4*)&dblt[(size_t)(8 + s) * NN + t0 + c4];
    }
    float A0 = -expf(A_log[d * DS + s0]);
    float A1 = -expf(A_log[d * DS + s0 + 1]);
    __syncthreads();
    {   // dt tile: 32 d x 64 t
        int row = tid >> 3;
        int tb = (tid & 7) * 8;
        int dd = dblk * 32 + row;
        float bd = b_dt[dd];
        float wv[8];
#pragma unroll
        for (int j = 0; j < 8; j++) wv[j] = W_dt[j * DI + dd];
#pragma unroll
        for (int j = 0; j < 8; j++) {
            int t = tb + j;
            float acc = bd;
#pragma unroll
            for (int k = 0; k < 8; k++) acc = fmaf(D8[k][t], wv[k], acc);
            Td[row][t] = softplusf(acc);
        }
    }
    __syncthreads();
    float h0 = 0.f, h1 = 0.f, P0 = 1.f, P1 = 1.f;
    for (int i = 0; i < CHLEN; i += 4) {
        float4 d4 = *(const float4*)&Td[dloc][i];
        float4 x4 = *(const float4*)&Tx[dloc][i];
        float4 b04 = *(const float4*)&Bs[s0][i];
        float4 b14 = *(const float4*)&Bs[s0 + 1][i];
#define P1S(U) { float dtv = d4.U; float a0 = __expf(dtv * A0); float a1 = __expf(dtv * A1); \
        float dx = dtv * x4.U; h0 = fmaf(a0, h0, dx * b04.U); h1 = fmaf(a1, h1, dx * b14.U); \
        P0 *= a0; P1 *= a1; }
        P1S(x) P1S(y) P1S(z) P1S(w)
#undef P1S
    }
    int idx = chunk * 4096 + d * DS + s0;
    float2 vP; vP.x = P0; vP.y = P1;
    float2 vH; vH.x = h0; vH.y = h1;
    *(float2*)(chkP + idx) = vP;
    *(float2*)(chkH + idx) = vH;
}

// single phase2: serial over all chunks with 8-deep batched prefetch
__global__ void scan_phase2(const float* __restrict__ chkP, const float* __restrict__ chkH,
                            float* __restrict__ init) {
    int idx = blockIdx.x * blockDim.x + threadIdx.x;  // 4096 total
    float h = 0.f;
    for (int c0 = 0; c0 < NCH; c0 += 8) {
        float p[8], q[8];
#pragma unroll
        for (int j = 0; j < 8; j++) {
            p[j] = chkP[(c0 + j) * 4096 + idx];
            q[j] = chkH[(c0 + j) * 4096 + idx];
        }
#pragma unroll
        for (int j = 0; j < 8; j++) {
            init[(c0 + j) * 4096 + idx] = h;
            h = fmaf(p[j], h, q[j]);
        }
    }
}

// phase3: D8 overlaid into Cs buffer; sz prefetched into registers before the scan loop
__global__ __launch_bounds__(256, 6) void scan_phase3(const float* __restrict__ xst,
                                                      const float* __restrict__ dblt,
                                                      const float* __restrict__ A_log,
                                                      const float* __restrict__ W_dt,
                                                      const float* __restrict__ b_dt,
                                                      const float* __restrict__ init,
                                                      const float* __restrict__ D_p,
                                                      const float* __restrict__ szt,
                                                      float* __restrict__ yt) {
    __shared__ float Td[32][68];
    __shared__ float Tx[32][68];
    __shared__ float Bs[16][68];
    __shared__ float CsD8[16][68];   // rows 0..7 = D8 during dt compute; then C rows 0..15
    int tid = threadIdx.x;
    int wave = tid >> 6, lane = tid & 63;
    int sg = lane & 7, dl = lane >> 3;
    int dblk = blockIdx.x, chunk = blockIdx.y;
    int t0 = chunk * CHLEN;
    int dloc = wave * 8 + dl;
    int d = dblk * 32 + dloc;
    int s0 = 2 * sg;
#pragma unroll
    for (int p = 0; p < 2; p++) {
        int linear = tid + p * 256;
        int row = linear >> 4, c4 = (linear & 15) * 4;
        *(float4*)&Tx[row][c4] = *(const float4*)&xst[(size_t)(dblk * 32 + row) * NN + t0 + c4];
    }
    if (tid < 128) {
        int r = tid >> 4, c4 = (tid & 15) * 4;
        *(float4*)&CsD8[r][c4] = *(const float4*)&dblt[(size_t)r * NN + t0 + c4];  // D8
    }
    {
        int s = tid >> 4, c4 = (tid & 15) * 4;
        *(float4*)&Bs[s][c4] = *(const float4*)&dblt[(size_t)(8 + s) * NN + t0 + c4];
    }
    float A0 = -expf(A_log[d * DS + s0]);
    float A1 = -expf(A_log[d * DS + s0 + 1]);
    float Dd = D_p[d];
    float2 ini = *(const float2*)(init + chunk * 4096 + d * DS + s0);
    float h0 = ini.x, h1 = ini.y;
    __syncthreads();
    {   // dt tile from D8 (CsD8 rows 0..7)
        int row = tid >> 3;
        int tb = (tid & 7) * 8;
        int dd = dblk * 32 + row;
        float bd = b_dt[dd];
        float wv[8];
#pragma unroll
        for (int j = 0; j < 8; j++) wv[j] = W_dt[j * DI + dd];
#pragma unroll
        for (int j = 0; j < 8; j++) {
            int t = tb + j;
            float acc = bd;
#pragma unroll
            for (int k = 0; k < 8; k++) acc = fmaf(CsD8[k][t], wv[k], acc);
            Td[row][t] = softplusf(acc);
        }
    }
    __syncthreads();
    {   // now load C rows over the dead D8
        int s = tid >> 4, c4 = (tid & 15) * 4;
        *(float4*)&CsD8[s][c4] = *(const float4*)&dblt[(size_t)(24 + s) * NN + t0 + c4];
    }
    // prefetch sz for the store epilogue (8 independent loads, hidden under the scan)
    float szv[8];
#pragma unroll
    for (int r = 0; r < 8; r++)
        szv[r] = szt[(size_t)(dblk * 32 + wave * 8 + r) * NN + t0 + lane];
    __syncthreads();
    for (int i = 0; i < CHLEN; i += 4) {
        float4 d4 = *(const float4*)&Td[dloc][i];
        float4 x4 = *(const float4*)&Tx[dloc][i];
        float4 b04 = *(const float4*)&Bs[s0][i];
        float4 b14 = *(const float4*)&Bs[s0 + 1][i];
        float4 c04 = *(const float4*)&CsD8[s0][i];
        float4 c14 = *(const float4*)&CsD8[s0 + 1][i];
        float4 yv;
#define P3S(U) { float dtv = d4.U; float a0 = __expf(dtv * A0); float a1 = __expf(dtv * A1); \
        float dx = dtv * x4.U; h0 = fmaf(a0, h0, dx * b04.U); h1 = fmaf(a1, h1, dx * b14.U); \
        float c = fmaf(h1, c14.U, h0 * c04.U); \
        c += __shfl_xor(c, 1); c += __shfl_xor(c, 2); c += __shfl_xor(c, 4); \
        yv.U = c + Dd * x4.U; }
        P3S(x) P3S(y) P3S(z) P3S(w)
#undef P3S
        if (sg == 0) *(float4*)&Td[dloc][i] = yv;  // in-place: this wave's row only
    }
#pragma unroll
    for (int r = 0; r < 8; r++) {
        int row = wave * 8 + r;
        yt[(size_t)(dblk * 32 + row) * NN + t0 + lane] = Td[row][lane] * szv[r];
    }
}

// ---------------------------------------------------------------- output heads (ge_norm folded in)
__global__ void heads_kernel(const float* __restrict__ ge, const int* __restrict__ counts,
                             const float* Wc, const float* bc, const float* Wh, const float* bh,
                             const float* Wt, const float* bt, const float* Wp1, const float* bp1,
                             const float* Wp2, const float* bp2, const float* Wd, const float* bd,
                             const float* Ws, const float* bs, float* __restrict__ out) {
    int col = blockIdx.x * blockDim.x + threadIdx.x;
    int b = blockIdx.y;
    if (col >= OUTW) return;
    const float* W; const float* bi; int lc, w;
    if (col < 1)         { W = Wc;  bi = bc;  lc = col;        w = 1; }
    else if (col < 5)    { W = Wh;  bi = bh;  lc = col - 1;    w = 4; }
    else if (col < 8)    { W = Wt;  bi = bt;  lc = col - 5;    w = 3; }
    else if (col < 520)  { W = Wp1; bi = bp1; lc = col - 8;    w = 512; }
    else if (col < 1032) { W = Wp2; bi = bp2; lc = col - 520;  w = 512; }
    else if (col < 1544) { W = Wd;  bi = bd;  lc = col - 1032; w = 512; }
    else                 { W = Ws;  bi = bs;  lc = col - 1544; w = 8; }
    float scale = 1.f / fmaxf((float)counts[b], 1.f);
    float dot = 0.f;
#pragma unroll 8
    for (int f = 0; f < HH; f++) dot = fmaf(ge[b * HH + f], W[f * w + lc], dot);
    out[(size_t)b * OUTW + col] = bi[lc] + scale * dot;
}

// ---------------------------------------------------------------- launch
extern "C" void kernel_launch(void* const* d_in, const int* in_sizes, int n_in,
                              void* d_out, int out_size, void* d_ws, size_t ws_size,
                              hipStream_t stream) {
    const float* nf      = (const float*)d_in[0];
    const int*   ei      = (const int*)d_in[1];
    const int*   batch   = (const int*)d_in[2];
    const float* W_in    = (const float*)d_in[3];
    const float* b_in    = (const float*)d_in[4];
    const float* W_g1    = (const float*)d_in[5];
    const float* b_g1    = (const float*)d_in[6];
    const float* W_g2    = (const float*)d_in[7];
    const float* b_g2    = (const float*)d_in[8];
    const float* W_inproj= (const float*)d_in[9];
    const float* conv_w  = (const float*)d_in[10];
    const float* conv_b  = (const float*)d_in[11];
    const float* W_xproj = (const float*)d_in[12];
    const float* W_dt    = (const float*)d_in[13];
    const float* b_dt    = (const float*)d_in[14];
    const float* A_log   = (const float*)d_in[15];
    const float* D_p     = (const float*)d_in[16];
    const float* W_out   = (const float*)d_in[17];
    const float* gamma   = (const float*)d_in[18];
    const float* beta    = (const float*)d_in[19];
    const float* Wc = (const float*)d_in[20]; const float* bc = (const float*)d_in[21];
    const float* Wh = (const float*)d_in[22]; const float* bh = (const float*)d_in[23];
    const float* Wt = (const float*)d_in[24]; const float* bt = (const float*)d_in[25];
    const float* Wp1= (const float*)d_in[26]; const float* bp1= (const float*)d_in[27];
    const float* Wp2= (const float*)d_in[28]; const float* bp2= (const float*)d_in[29];
    const float* Wd = (const float*)d_in[30]; const float* bd = (const float*)d_in[31];
    const float* Ws = (const float*)d_in[32]; const float* bs = (const float*)d_in[33];

    const int* e_src = ei;
    const int* e_dst = ei + EE;

    // workspace layout (floats, then ints)
    float* w = (float*)d_ws;
    size_t o = 0;
    float* F0   = w + o; o += (size_t)NN * HH;   // dead during scan -> CHP/CHH
    float* F1   = w + o; o += (size_t)NN * HH;   // dead during scan -> INI
    float* F2   = w + o; o += (size_t)NN * HH;
    float* XZT  = w + o; o += (size_t)NN * 512;  // xz TRANSPOSED [512][NN]; dead after conv:
    float* YT   = XZT;                            //   y^T [DI][NN]
    float* XST  = w + o; o += (size_t)NN * DI;   // x (conv+silu), transposed [DI][NN]
    float* SZT  = w + o; o += (size_t)NN * DI;   // silu(z), transposed [DI][NN]
    float* DBLT = w + o; o += (size_t)NN * 40;   // [40][NN]; 0..7 = dt-proj^T, 8..23 = B^T, 24..39 = C^T
    float* GE   = w + o; o += BB * HH;
    float* DINV = w + o; o += NN;
    int* ip = (int*)(w + o);
    int* CNT    = ip; ip += NN;
    int* ROWPTR = ip; ip += NN + 1;
    int* CURSOR = ip; ip += NN;
    int* COL    = ip; ip += EE;
    int* COUNTS = ip; ip += BB;

    // overlays (regions dead during the scan)
    float* CHP  = F0;                         // NCH*4096 = 1M floats
    float* CHH  = F0 + (size_t)NCH * 4096;    // 1M floats (F0 holds 2M)
    float* INI  = F1;                         // NCH*4096 = 1M floats (F1 holds 2M)

    // zero scratch (single kernel instead of 3 memsets)
    zero_kernel<<<(NN + 255) / 256, 256, 0, stream>>>(CNT, GE, COUNTS);

    // CSR build
    deg_kernel<<<EE / 256, 256, 0, stream>>>(e_dst, CNT);
    prefix_kernel<<<1, 1024, 0, stream>>>(CNT, ROWPTR, CURSOR, DINV);
    scatter_kernel<<<EE / 256, 256, 0, stream>>>(e_src, e_dst, CURSOR, COL);

    // xw1 = relu(nf @ W_in + b_in) @ W_g1  (h0 never materialized)
    gemm_in_g1<<<dim3(2, NN / 64), 256, 0, stream>>>(nf, W_in, b_in, W_g1, F1);
    gcn_gather4<<<NN / 8, 256, 0, stream>>>(F1, ROWPTR, COL, DINV, b_g1, F0);
    // GCN layer 2
    gemm_k<<<dim3(2, NN / 64), 256, 0, stream>>>(F0, W_g2, nullptr, F1, NN, HH, HH, 0);
    gcn_gather4<<<NN / 8, 256, 0, stream>>>(F1, ROWPTR, COL, DINV, b_g2, F2);  // F2 = h_gnn

    // xz^T = (h_gnn @ W_inproj)^T  (transposed store: both consumers want [512][NN])
    gemm_big512_t<<<dim3(4, NN / 128), 512, 0, stream>>>(F2, W_inproj, XZT, NN, 512, HH);
    // conv + silu over contiguous rows -> XST; silu(z) -> SZT (pure streaming, no LDS)
    conv_silu_rows<<<dim3(NN / 1024, 512), 256, 0, stream>>>(XZT, conv_w, conv_b, XST, SZT);
    // dbl = xs @ W_xproj, written directly transposed -> DBLT (fused)
    gemm_at_dblt<<<NN / 64, 256, 0, stream>>>(XST, W_xproj, DBLT);

    // Mamba scan (dt fused into phase1/phase3; single phase2)
    scan_phase1<<<dim3(8, NCH), 256, 0, stream>>>(XST, DBLT, A_log, W_dt, b_dt, CHP, CHH);
    scan_phase2<<<16, 256, 0, stream>>>(CHP, CHH, INI);
    scan_phase3<<<dim3(8, NCH), 256, 0, stream>>>(XST, DBLT, A_log, W_dt, b_dt, INI, D_p, SZT, YT);

    // h_mamba = y @ W_out; + h_gnn; LayerNorm; pooled directly into GE (h_final never stored)
    gemm_at_ln_pool<<<NN / 32, 256, 0, stream>>>(YT, W_out, F2, gamma, beta, batch, GE, COUNTS);

    // heads (ge_norm folded in)
    heads_kernel<<<dim3((OUTW + 127) / 128, BB), 128, 0, stream>>>(
        GE, COUNTS, Wc, bc, Wh, bh, Wt, bt, Wp1, bp1, Wp2, bp2, Wd, bd, Ws, bs, (float*)d_out);
}